// Round 1
// baseline (1935.771 us; speedup 1.0000x reference)
//
#include <hip/hip_runtime.h>
#include <hip/hip_bf16.h>

#define N_NODES 100000
#define N_EDGES 600000
#define SCAN_BLOCKS ((N_NODES + 255) / 256)   // 391

typedef __bf16 bf16;
typedef __bf16 bf16x2 __attribute__((ext_vector_type(2)));
typedef __bf16 bf16x4 __attribute__((ext_vector_type(4)));
typedef __bf16 bf16x8 __attribute__((ext_vector_type(8)));
typedef float f32x4 __attribute__((ext_vector_type(4)));

// ---------------------------------------------------------------------------
// deg[n] = #edges with from==n (== to-degree by reverse-pair symmetry)
__global__ void deg_hist(const int* __restrict__ from, int* __restrict__ deg, int E) {
    int e = blockIdx.x * blockDim.x + threadIdx.x;
    if (e < E) atomicAdd(&deg[from[e]], 1);
}

// ---- CSR build ----
__global__ __launch_bounds__(256) void block_sums(
    const int* __restrict__ deg, int* __restrict__ bsum)
{
    __shared__ int s[256];
    int i = blockIdx.x * 256 + threadIdx.x;
    s[threadIdx.x] = (i < N_NODES) ? deg[i] : 0;
    __syncthreads();
    for (int st = 128; st > 0; st >>= 1) {
        if (threadIdx.x < st) s[threadIdx.x] += s[threadIdx.x + st];
        __syncthreads();
    }
    if (threadIdx.x == 0) bsum[blockIdx.x] = s[0];
}

__global__ __launch_bounds__(256) void scan_partials(
    const int* __restrict__ bsum, int* __restrict__ bpref, int* __restrict__ off)
{
    __shared__ int s[SCAN_BLOCKS];
    for (int i = threadIdx.x; i < SCAN_BLOCKS; i += 256) s[i] = bsum[i];
    __syncthreads();
    if (threadIdx.x == 0) {
        int run = 0;
        for (int i = 0; i < SCAN_BLOCKS; i++) { int t = s[i]; s[i] = run; run += t; }
        off[N_NODES] = run;   // == N_EDGES
    }
    __syncthreads();
    for (int i = threadIdx.x; i < SCAN_BLOCKS; i += 256) bpref[i] = s[i];
}

__global__ __launch_bounds__(256) void block_scan(
    const int* __restrict__ deg, const int* __restrict__ bpref,
    int* __restrict__ off, int* __restrict__ cursor)
{
    __shared__ int s[256];
    int i = blockIdx.x * 256 + threadIdx.x;
    int v = (i < N_NODES) ? deg[i] : 0;
    s[threadIdx.x] = v;
    __syncthreads();
    for (int st = 1; st < 256; st <<= 1) {
        int x = (threadIdx.x >= st) ? s[threadIdx.x - st] : 0;
        __syncthreads();
        s[threadIdx.x] += x;
        __syncthreads();
    }
    if (i < N_NODES) {
        int o = bpref[blockIdx.x] + s[threadIdx.x] - v;   // exclusive
        off[i] = o;
        cursor[i] = o;
    }
}

// se[p] = e (sorted by from), rank[e] = p
__global__ void scatter_csr(const int* __restrict__ from, int* __restrict__ cursor,
                            int* __restrict__ se, int* __restrict__ rank, int E) {
    int e = blockIdx.x * blockDim.x + threadIdx.x;
    if (e < E) {
        int p = atomicAdd(&cursor[from[e]], 1);
        se[p] = e;
        rank[e] = p;
    }
}

// fromP[i] = from[se[i]]; backP[i] = rank[se[i]^1]
__global__ void make_maps(const int* __restrict__ se, const int* __restrict__ from,
                          const int* __restrict__ rank,
                          int* __restrict__ fromP, int* __restrict__ backP, int E) {
    int i = blockIdx.x * blockDim.x + threadIdx.x;
    if (i < E) {
        int e = se[i];
        fromP[i] = from[e];
        backP[i] = rank[e ^ 1];
    }
}

// ---------------------------------------------------------------------------
// C[M,128] = A[M,64] @ B[64,128] + bias   (node-side GEMM, K=64, fp32 vector)
__global__ __launch_bounds__(256) void node_gemm(
    const float* __restrict__ A, const float* __restrict__ B,
    const float* __restrict__ bias, float* __restrict__ C, int M)
{
    __shared__ float As[16][65];
    __shared__ float Bs[16][128];
    int row0 = blockIdx.x * 64;
    int tid = threadIdx.x;
    int tx = tid & 15, ty = tid >> 4;
    float acc[4][8];
    #pragma unroll
    for (int i = 0; i < 4; i++)
        #pragma unroll
        for (int j = 0; j < 8; j++) acc[i][j] = 0.f;

    for (int kk = 0; kk < 64; kk += 16) {
        int m  = tid >> 2;
        int k4 = (tid & 3) * 4;
        float4 v = make_float4(0.f, 0.f, 0.f, 0.f);
        if (row0 + m < M)
            v = *(const float4*)(A + (size_t)(row0 + m) * 64 + kk + k4);
        As[k4 + 0][m] = v.x; As[k4 + 1][m] = v.y;
        As[k4 + 2][m] = v.z; As[k4 + 3][m] = v.w;
        #pragma unroll
        for (int t = 0; t < 2; t++) {
            int id = tid + t * 256;
            int k = id >> 5, n4 = (id & 31) * 4;
            *(float4*)(&Bs[k][n4]) = *(const float4*)(B + (size_t)(kk + k) * 128 + n4);
        }
        __syncthreads();
        #pragma unroll
        for (int k = 0; k < 16; k++) {
            float a[4], b[8];
            #pragma unroll
            for (int i = 0; i < 4; i++) a[i] = As[k][ty * 4 + i];
            #pragma unroll
            for (int j = 0; j < 8; j++) b[j] = Bs[k][tx + j * 16];
            #pragma unroll
            for (int i = 0; i < 4; i++)
                #pragma unroll
                for (int j = 0; j < 8; j++) acc[i][j] += a[i] * b[j];
        }
        __syncthreads();
    }
    #pragma unroll
    for (int i = 0; i < 4; i++) {
        int r = row0 + ty * 4 + i;
        if (r < M) {
            #pragma unroll
            for (int j = 0; j < 8; j++) {
                int c = tx + j * 16;
                C[(size_t)r * 128 + c] = acc[i][j] + bias[c];
            }
        }
    }
}

// ---------------------------------------------------------------------------
// baseP[i,:] = bf16( nodeW1[fromP[i],:] + ef[se[i],:16]@W2 + (W2_b+W3_b) )
__global__ __launch_bounds__(256) void base_sorted(
    const float* __restrict__ nodeW1, const int* __restrict__ fromP,
    const int* __restrict__ se, const float* __restrict__ ef,
    const float* __restrict__ W2, const float* __restrict__ W2b,
    const float* __restrict__ W3b, bf16* __restrict__ baseP)
{
    int tid = threadIdx.x;
    int c0 = (tid & 31) * 4;
    int sub = tid >> 5;                  // 8 edge slots
    float4 w[16];
    #pragma unroll
    for (int k = 0; k < 16; k++) w[k] = *(const float4*)(W2 + k * 128 + c0);
    float4 bias;
    {
        float4 a = *(const float4*)(W2b + c0);
        float4 b = *(const float4*)(W3b + c0);
        bias = make_float4(a.x + b.x, a.y + b.y, a.z + b.z, a.w + b.w);
    }
    #pragma unroll 1
    for (int it = 0; it < 64; ++it) {
        int i = blockIdx.x * 512 + it * 8 + sub;
        if (i >= N_EDGES) break;
        const float* efr = ef + (size_t)se[i] * 16;
        float4 nv = *(const float4*)(nodeW1 + (size_t)fromP[i] * 128 + c0);
        float4 acc = make_float4(bias.x + nv.x, bias.y + nv.y,
                                 bias.z + nv.z, bias.w + nv.w);
        #pragma unroll
        for (int k = 0; k < 16; k++) {
            float s = efr[k];
            acc.x += s * w[k].x; acc.y += s * w[k].y;
            acc.z += s * w[k].z; acc.w += s * w[k].w;
        }
        bf16x4 o;
        o[0] = (bf16)acc.x; o[1] = (bf16)acc.y; o[2] = (bf16)acc.z; o[3] = (bf16)acc.w;
        *(bf16x4*)(baseP + (size_t)i * 128 + c0) = o;
    }
}

// ---------------------------------------------------------------------------
// W3T[n][k] = bf16(W3[k][n]);  U2T[n][k] = bf16(U2[k][n])   (one-time)
__global__ __launch_bounds__(256) void prep_weights(
    const float* __restrict__ W3, const float* __restrict__ U2,
    bf16* __restrict__ W3T, bf16* __restrict__ U2T)
{
    int i = blockIdx.x * 256 + threadIdx.x;
    if (i < 128 * 128) {
        int k = i >> 7, n = i & 127;
        W3T[n * 128 + k] = (bf16)W3[k * 128 + n];
        U2T[n * 128 + k] = (bf16)U2[k * 128 + n];
    }
}

// ---------------------------------------------------------------------------
// Edge-step GEMM v3 (bf16 MFMA) with FUSED per-node segment sum.
//   A[i,:] = fused ? relu(baseP[i] + Sin[fromP[i]] - gin[backP[i]]) : relu(baseP[i])
//   gout[orow(i),:] = bf16(A @ B)   (orow = backP[i] when scatter, else i)
// Block = 256 sorted rows; wave w owns rows w*64..w*64+63.
// do_seg: after the main loop each wave re-reads its OWN 64 output rows
// (L1/L2-hot, written by itself) and segment-sums them into fp32 Sout.
// Buckets fully inside the 64-row subrange -> plain store; buckets crossing a
// subrange boundary -> atomicAdd (Sout pre-zeroed by host-side memset).
__global__ __launch_bounds__(256) void edge_mfma_v3(
    const bf16* __restrict__ baseP, const bf16* __restrict__ gin,
    const float* __restrict__ Sin, const int* __restrict__ fromP,
    const int* __restrict__ backP, const int* __restrict__ off,
    const bf16* __restrict__ BT, bf16* __restrict__ gout,
    float* __restrict__ Sout, int fused, int do_seg, int scatter)
{
    __shared__ bf16 Bsw[128 * 128];   // 32 KB
    int tid = threadIdx.x;

    // stage B, destination-consecutive (bank-conflict-free LDS writes)
    #pragma unroll
    for (int t = 0; t < 8; t++) {
        int c = tid + t * 256;            // dst chunk id 0..2047
        int cmr = c & 15;
        int cq  = (c >> 4) & 3;
        int ckt = (c >> 6) & 3;
        int cn  = c >> 8;
        int brow = cn * 16 + cmr;
        int bcol = ckt * 32 + cq * 8;
        *(bf16x8*)&Bsw[(size_t)c * 8] =
            *(const bf16x8*)(BT + (size_t)brow * 128 + bcol);
    }
    __syncthreads();

    int wave = tid >> 6, lane = tid & 63;
    int quad = lane >> 4, mr = lane & 15;

    #pragma unroll 1
    for (int it = 0; it < 4; ++it) {
        int i0 = blockIdx.x * 256 + wave * 64 + it * 16;
        if (i0 >= N_EDGES) break;         // tail block (full 16-groups only)
        int i = i0 + mr;

        // ---- build this lane's 4 A-fragments in registers ----
        bf16x8 afr[4];
        if (!fused) {
            #pragma unroll
            for (int kt = 0; kt < 4; kt++) {
                bf16x8 bb = *(const bf16x8*)(baseP + (size_t)i * 128 + kt * 32 + quad * 8);
                #pragma unroll
                for (int j = 0; j < 8; j++)
                    afr[kt][j] = (bf16)fmaxf((float)bb[j], 0.f);
            }
        } else {
            const float* sr = Sin + (size_t)fromP[i] * 128;
            const bf16*  gr = gin + (size_t)backP[i] * 128;
            #pragma unroll
            for (int kt = 0; kt < 4; kt++) {
                int c = kt * 32 + quad * 8;
                bf16x8 bb = *(const bf16x8*)(baseP + (size_t)i * 128 + c);
                bf16x8 gg = *(const bf16x8*)(gr + c);
                float4 s0 = *(const float4*)(sr + c);
                float4 s1 = *(const float4*)(sr + c + 4);
                float sv[8] = {s0.x, s0.y, s0.z, s0.w, s1.x, s1.y, s1.z, s1.w};
                #pragma unroll
                for (int j = 0; j < 8; j++) {
                    float v = (float)bb[j] + sv[j] - (float)gg[j];
                    afr[kt][j] = (bf16)fmaxf(v, 0.f);
                }
            }
        }

        // ---- MFMA: 8 col-tiles x 4 k-chunks ----
        f32x4 acc[8];
        #pragma unroll
        for (int n = 0; n < 8; n++) acc[n] = (f32x4){0.f, 0.f, 0.f, 0.f};
        #pragma unroll
        for (int kt = 0; kt < 4; kt++) {
            #pragma unroll
            for (int n = 0; n < 8; n++) {
                bf16x8 b = *(const bf16x8*)&Bsw[(size_t)(((n * 4 + kt) * 64) + lane) * 8];
                acc[n] = __builtin_amdgcn_mfma_f32_16x16x32_bf16(afr[kt], b, acc[n], 0, 0, 0);
            }
        }

        // ---- epilogue: C/D layout col=mr, row=quad*4+reg; pack bf16x2 via
        // lane-pair shfl -> 4B stores, 64B segments. Optional scatter to backP.
        int rbase4 = i0 + quad * 4;
        int orow[4];
        #pragma unroll
        for (int reg = 0; reg < 4; reg++)
            orow[reg] = scatter ? backP[rbase4 + reg] : (rbase4 + reg);

        #pragma unroll
        for (int np = 0; np < 4; np++) {
            int n0 = np * 2;
            #pragma unroll
            for (int reg = 0; reg < 4; reg++) {
                float v0 = acc[n0][reg], v1 = acc[n0 + 1][reg];
                float o0 = __shfl_xor(v0, 1);
                float o1 = __shfl_xor(v1, 1);
                bf16x2 pk;
                int colb;
                if ((mr & 1) == 0) {
                    pk[0] = (bf16)v0; pk[1] = (bf16)o0;
                    colb = n0 * 16 + mr;
                } else {
                    pk[0] = (bf16)o1; pk[1] = (bf16)v1;
                    colb = (n0 + 1) * 16 + (mr ^ 1);
                }
                *(bf16x2*)(gout + (size_t)orow[reg] * 128 + colb) = pk;
            }
        }
    }

    // ---- fused segment sum over this wave's own 64 output rows ----
    if (do_seg) {
        __syncthreads();   // drains vmcnt: our stores are L1/L2-visible
        int rbase = blockIdx.x * 256 + wave * 64;
        int rend  = rbase + 64;
        if (rend > N_EDGES) rend = N_EDGES;
        int r = rbase;
        while (r < rend) {
            int n  = fromP[r];        // wave-uniform (broadcast load)
            int bs = off[n], be = off[n + 1];
            int e  = be < rend ? be : rend;
            float a0 = 0.f, a1 = 0.f;
            for (int j = r; j < e; ++j) {
                bf16x2 v = *(const bf16x2*)(gout + (size_t)j * 128 + lane * 2);
                a0 += (float)v[0];
                a1 += (float)v[1];
            }
            float* sp = Sout + (size_t)n * 128 + lane * 2;
            if (bs >= rbase && be <= rend) {
                *(float2*)sp = make_float2(a0, a1);      // bucket fully ours
            } else {
                atomicAdd(sp, a0);                        // boundary bucket
                atomicAdd(sp + 1, a1);
            }
            r = e;
        }
    }
}

// ---------------------------------------------------------------------------
// Readout (fused): gB holds U2vu rows scattered to backP order, so the
// in-edge sum of node n is the CONTIGUOUS range [off[n], off[n+1]).
// out[n,:] = relu(U1x[n,:] + sum_bucket(gB) + deg[n]*U2b[:])
__global__ __launch_bounds__(256) void segsum_final_fused(
    const bf16* __restrict__ gB, const int* __restrict__ off,
    const float* __restrict__ U1x, const float* __restrict__ U2b,
    float* __restrict__ out)
{
    int n = blockIdx.x * 4 + (threadIdx.x >> 6);
    if (n >= N_NODES) return;
    int lane = threadIdx.x & 63;
    int o0 = off[n], o1 = off[n + 1];
    float a0 = 0.f, a1 = 0.f;
    for (int i = o0; i < o1; ++i) {
        bf16x2 v = *(const bf16x2*)(gB + (size_t)i * 128 + lane * 2);
        a0 += (float)v[0];
        a1 += (float)v[1];
    }
    float d = (float)(o1 - o0);
    float2 u = *(const float2*)(U1x + (size_t)n * 128 + lane * 2);
    float2 b = *(const float2*)(U2b + lane * 2);
    float r0 = fmaxf(u.x + a0 + d * b.x, 0.f);
    float r1 = fmaxf(u.y + a1 + d * b.y, 0.f);
    *(float2*)(out + (size_t)n * 128 + lane * 2) = make_float2(r0, r1);
}

// ---------------------------------------------------------------------------
extern "C" void kernel_launch(void* const* d_in, const int* in_sizes, int n_in,
                              void* d_out, int out_size, void* d_ws, size_t ws_size,
                              hipStream_t stream) {
    const float* nf  = (const float*)d_in[0];
    const float* ef  = (const float*)d_in[1];
    // d_in[2] edge_hiddens: zeros -> h1 = relu(base); first GEMM uses fused=0
    const int* edges = (const int*)d_in[3];
    const int* from  = edges;
    const float* W1w = (const float*)d_in[4];
    const float* W1b = (const float*)d_in[5];
    const float* W2w = (const float*)d_in[6];
    const float* W2b = (const float*)d_in[7];
    const float* W3w = (const float*)d_in[8];
    const float* W3b = (const float*)d_in[9];
    const float* U1w = (const float*)d_in[10];
    const float* U1b = (const float*)d_in[11];
    const float* U2w = (const float*)d_in[12];
    const float* U2b = (const float*)d_in[13];
    float* out = (float*)d_out;

    const size_t NODE_MAT = (size_t)N_NODES * 128;
    const size_t EDGE_MAT = (size_t)N_EDGES * 128;
    char* w = (char*)d_ws;
    float* nodeW1 = (float*)w; w += NODE_MAT * 4;        // reused as U1x
    float* SA     = (float*)w; w += NODE_MAT * 4;        // fp32 S ping
    float* SB     = (float*)w; w += NODE_MAT * 4;        // fp32 S pong
    bf16*  baseP  = (bf16*)w;  w += EDGE_MAT * 2;
    bf16*  g0     = (bf16*)w;  w += EDGE_MAT * 2;
    bf16*  g1     = (bf16*)w;  w += EDGE_MAT * 2;
    bf16*  W3T    = (bf16*)w;  w += 128 * 128 * 2;
    bf16*  U2T    = (bf16*)w;  w += 128 * 128 * 2;
    int*   deg    = (int*)w;   w += (size_t)N_NODES * 4;
    int*   off    = (int*)w;   w += (size_t)(N_NODES + 1) * 4;
    int*   cursor = (int*)w;   w += (size_t)N_NODES * 4;
    int*   bsum   = (int*)w;   w += (size_t)SCAN_BLOCKS * 4;
    int*   bpref  = (int*)w;   w += (size_t)SCAN_BLOCKS * 4;
    int*   se     = (int*)w;   w += (size_t)N_EDGES * 4;
    int*   rank   = (int*)w;   w += (size_t)N_EDGES * 4;
    int*   fromP  = (int*)w;   w += (size_t)N_EDGES * 4;
    int*   backP  = (int*)w;   w += (size_t)N_EDGES * 4;

    // ---- CSR build + sorted-space maps ----
    hipMemsetAsync(deg, 0, (size_t)N_NODES * 4, stream);
    deg_hist<<<(N_EDGES + 255) / 256, 256, 0, stream>>>(from, deg, N_EDGES);
    block_sums<<<SCAN_BLOCKS, 256, 0, stream>>>(deg, bsum);
    scan_partials<<<1, 256, 0, stream>>>(bsum, bpref, off);
    block_scan<<<SCAN_BLOCKS, 256, 0, stream>>>(deg, bpref, off, cursor);
    scatter_csr<<<(N_EDGES + 255) / 256, 256, 0, stream>>>(from, cursor, se, rank, N_EDGES);
    make_maps<<<(N_EDGES + 255) / 256, 256, 0, stream>>>(se, from, rank, fromP, backP, N_EDGES);

    // ---- loop-invariant precompute ----
    prep_weights<<<(128 * 128 + 255) / 256, 256, 0, stream>>>(W3w, U2w, W3T, U2T);
    node_gemm<<<(N_NODES + 63) / 64, 256, 0, stream>>>(nf, W1w, W1b, nodeW1, N_NODES);
    base_sorted<<<(N_EDGES + 511) / 512, 256, 0, stream>>>(
        nodeW1, fromP, se, ef, W2w, W2b, W3b, baseP);

    // ---- message passing: 5 W3-steps with fused segsum, then readout ----
    const int EGRID = (N_EDGES + 255) / 256;   // 2344
    const size_t SBYTES = NODE_MAT * 4;

    hipMemsetAsync(SA, 0, SBYTES, stream);
    edge_mfma_v3<<<EGRID, 256, 0, stream>>>(          // h1; S1 -> SA
        baseP, g0, SB, fromP, backP, off, W3T, g0, SA, 0, 1, 0);
    hipMemsetAsync(SB, 0, SBYTES, stream);
    edge_mfma_v3<<<EGRID, 256, 0, stream>>>(          // h2; S2 -> SB
        baseP, g0, SA, fromP, backP, off, W3T, g1, SB, 1, 1, 0);
    hipMemsetAsync(SA, 0, SBYTES, stream);
    edge_mfma_v3<<<EGRID, 256, 0, stream>>>(          // h3; S3 -> SA
        baseP, g1, SB, fromP, backP, off, W3T, g0, SA, 1, 1, 0);
    hipMemsetAsync(SB, 0, SBYTES, stream);
    edge_mfma_v3<<<EGRID, 256, 0, stream>>>(          // h4; S4 -> SB
        baseP, g0, SA, fromP, backP, off, W3T, g1, SB, 1, 1, 0);
    hipMemsetAsync(SA, 0, SBYTES, stream);
    edge_mfma_v3<<<EGRID, 256, 0, stream>>>(          // h5; S5 -> SA
        baseP, g1, SB, fromP, backP, off, W3T, g0, SA, 1, 1, 0);

    // readout: h6 = relu(base + S5[from] - g5[back]); gB[backP[i]] = h6 @ U2
    edge_mfma_v3<<<EGRID, 256, 0, stream>>>(
        baseP, g0, SA, fromP, backP, off, U2T, g1, SB, 1, 0, 1);

    node_gemm<<<(N_NODES + 63) / 64, 256, 0, stream>>>(nf, U1w, U1b, nodeW1, N_NODES);
    segsum_final_fused<<<(N_NODES + 3) / 4, 256, 0, stream>>>(
        g1, off, nodeW1, U2b, out);
}

// Round 2
// 1851.714 us; speedup vs baseline: 1.0454x; 1.0454x over previous
//
#include <hip/hip_runtime.h>
#include <hip/hip_bf16.h>

#define N_NODES 100000
#define N_EDGES 600000
#define SCAN_BLOCKS ((N_NODES + 255) / 256)   // 391

typedef __bf16 bf16;
typedef __bf16 bf16x2 __attribute__((ext_vector_type(2)));
typedef __bf16 bf16x4 __attribute__((ext_vector_type(4)));
typedef __bf16 bf16x8 __attribute__((ext_vector_type(8)));
typedef float f32x4 __attribute__((ext_vector_type(4)));

// ---------------------------------------------------------------------------
// deg[n] = #edges with from==n (== to-degree by reverse-pair symmetry)
__global__ void deg_hist(const int* __restrict__ from, int* __restrict__ deg, int E) {
    int e = blockIdx.x * blockDim.x + threadIdx.x;
    if (e < E) atomicAdd(&deg[from[e]], 1);
}

// ---- CSR build ----
__global__ __launch_bounds__(256) void block_sums(
    const int* __restrict__ deg, int* __restrict__ bsum)
{
    __shared__ int s[256];
    int i = blockIdx.x * 256 + threadIdx.x;
    s[threadIdx.x] = (i < N_NODES) ? deg[i] : 0;
    __syncthreads();
    for (int st = 128; st > 0; st >>= 1) {
        if (threadIdx.x < st) s[threadIdx.x] += s[threadIdx.x + st];
        __syncthreads();
    }
    if (threadIdx.x == 0) bsum[blockIdx.x] = s[0];
}

__global__ __launch_bounds__(256) void scan_partials(
    const int* __restrict__ bsum, int* __restrict__ bpref, int* __restrict__ off)
{
    __shared__ int s[SCAN_BLOCKS];
    for (int i = threadIdx.x; i < SCAN_BLOCKS; i += 256) s[i] = bsum[i];
    __syncthreads();
    if (threadIdx.x == 0) {
        int run = 0;
        for (int i = 0; i < SCAN_BLOCKS; i++) { int t = s[i]; s[i] = run; run += t; }
        off[N_NODES] = run;   // == N_EDGES
    }
    __syncthreads();
    for (int i = threadIdx.x; i < SCAN_BLOCKS; i += 256) bpref[i] = s[i];
}

__global__ __launch_bounds__(256) void block_scan(
    const int* __restrict__ deg, const int* __restrict__ bpref,
    int* __restrict__ off, int* __restrict__ cursor)
{
    __shared__ int s[256];
    int i = blockIdx.x * 256 + threadIdx.x;
    int v = (i < N_NODES) ? deg[i] : 0;
    s[threadIdx.x] = v;
    __syncthreads();
    for (int st = 1; st < 256; st <<= 1) {
        int x = (threadIdx.x >= st) ? s[threadIdx.x - st] : 0;
        __syncthreads();
        s[threadIdx.x] += x;
        __syncthreads();
    }
    if (i < N_NODES) {
        int o = bpref[blockIdx.x] + s[threadIdx.x] - v;   // exclusive
        off[i] = o;
        cursor[i] = o;
    }
}

// se[p] = e (sorted by from); rank not needed in this pipeline
__global__ void scatter_csr(const int* __restrict__ from, int* __restrict__ cursor,
                            int* __restrict__ se, int E) {
    int e = blockIdx.x * blockDim.x + threadIdx.x;
    if (e < E) {
        int p = atomicAdd(&cursor[from[e]], 1);
        se[p] = e;
    }
}

// ---------------------------------------------------------------------------
// C[M,128] = A[M,64] @ B[64,128] + bias   (node-side GEMM, K=64, fp32 vector)
__global__ __launch_bounds__(256) void node_gemm(
    const float* __restrict__ A, const float* __restrict__ B,
    const float* __restrict__ bias, float* __restrict__ C, int M)
{
    __shared__ float As[16][65];
    __shared__ float Bs[16][128];
    int row0 = blockIdx.x * 64;
    int tid = threadIdx.x;
    int tx = tid & 15, ty = tid >> 4;
    float acc[4][8];
    #pragma unroll
    for (int i = 0; i < 4; i++)
        #pragma unroll
        for (int j = 0; j < 8; j++) acc[i][j] = 0.f;

    for (int kk = 0; kk < 64; kk += 16) {
        int m  = tid >> 2;
        int k4 = (tid & 3) * 4;
        float4 v = make_float4(0.f, 0.f, 0.f, 0.f);
        if (row0 + m < M)
            v = *(const float4*)(A + (size_t)(row0 + m) * 64 + kk + k4);
        As[k4 + 0][m] = v.x; As[k4 + 1][m] = v.y;
        As[k4 + 2][m] = v.z; As[k4 + 3][m] = v.w;
        #pragma unroll
        for (int t = 0; t < 2; t++) {
            int id = tid + t * 256;
            int k = id >> 5, n4 = (id & 31) * 4;
            *(float4*)(&Bs[k][n4]) = *(const float4*)(B + (size_t)(kk + k) * 128 + n4);
        }
        __syncthreads();
        #pragma unroll
        for (int k = 0; k < 16; k++) {
            float a[4], b[8];
            #pragma unroll
            for (int i = 0; i < 4; i++) a[i] = As[k][ty * 4 + i];
            #pragma unroll
            for (int j = 0; j < 8; j++) b[j] = Bs[k][tx + j * 16];
            #pragma unroll
            for (int i = 0; i < 4; i++)
                #pragma unroll
                for (int j = 0; j < 8; j++) acc[i][j] += a[i] * b[j];
        }
        __syncthreads();
    }
    #pragma unroll
    for (int i = 0; i < 4; i++) {
        int r = row0 + ty * 4 + i;
        if (r < M) {
            #pragma unroll
            for (int j = 0; j < 8; j++) {
                int c = tx + j * 16;
                C[(size_t)r * 128 + c] = acc[i][j] + bias[c];
            }
        }
    }
}

// ---------------------------------------------------------------------------
// base[i,:] = bf16( nodeW1[from[i],:] + ef[i,:16]@W2 + (W2_b+W3_b) )
// ORIGINAL edge order (streaming ef, gathered nodeW1 rows — one-time cost).
__global__ __launch_bounds__(256) void base_orig(
    const float* __restrict__ nodeW1, const int* __restrict__ from,
    const float* __restrict__ ef, const float* __restrict__ W2,
    const float* __restrict__ W2b, const float* __restrict__ W3b,
    bf16* __restrict__ base)
{
    int tid = threadIdx.x;
    int c0 = (tid & 31) * 4;
    int sub = tid >> 5;                  // 8 edge slots
    float4 w[16];
    #pragma unroll
    for (int k = 0; k < 16; k++) w[k] = *(const float4*)(W2 + k * 128 + c0);
    float4 bias;
    {
        float4 a = *(const float4*)(W2b + c0);
        float4 b = *(const float4*)(W3b + c0);
        bias = make_float4(a.x + b.x, a.y + b.y, a.z + b.z, a.w + b.w);
    }
    #pragma unroll 1
    for (int it = 0; it < 64; ++it) {
        int i = blockIdx.x * 512 + it * 8 + sub;
        if (i >= N_EDGES) break;
        const float* efr = ef + (size_t)i * 16;
        float4 nv = *(const float4*)(nodeW1 + (size_t)from[i] * 128 + c0);
        float4 acc = make_float4(bias.x + nv.x, bias.y + nv.y,
                                 bias.z + nv.z, bias.w + nv.w);
        #pragma unroll
        for (int k = 0; k < 16; k++) {
            float s = efr[k];
            acc.x += s * w[k].x; acc.y += s * w[k].y;
            acc.z += s * w[k].z; acc.w += s * w[k].w;
        }
        bf16x4 o;
        o[0] = (bf16)acc.x; o[1] = (bf16)acc.y; o[2] = (bf16)acc.z; o[3] = (bf16)acc.w;
        *(bf16x4*)(base + (size_t)i * 128 + c0) = o;
    }
}

// ---------------------------------------------------------------------------
// W3T[n][k] = bf16(W3[k][n]);  U2T[n][k] = bf16(U2[k][n])   (one-time)
__global__ __launch_bounds__(256) void prep_weights(
    const float* __restrict__ W3, const float* __restrict__ U2,
    bf16* __restrict__ W3T, bf16* __restrict__ U2T)
{
    int i = blockIdx.x * 256 + threadIdx.x;
    if (i < 128 * 128) {
        int k = i >> 7, n = i & 127;
        W3T[n * 128 + k] = (bf16)W3[k * 128 + n];
        U2T[n * 128 + k] = (bf16)U2[k * 128 + n];
    }
}

// ---------------------------------------------------------------------------
// Edge-step GEMM v4 (bf16 MFMA), ORIGINAL edge order. All heavy streams are
// sequential; the only gather is S[from[i]] into the small (25.6 MB) bf16 S
// buffer (L2/L3-hot). The backlink read is gin[i^1] — i0 is 16-aligned, so
// (i0+mr)^1 = i0+(mr^1): a lane-pair swap within the SAME tile, fully
// coalesced.
//   A[i,:] = fused ? relu(base[i] + S[from[i]] - gin[i^1]) : relu(base[i])
//   gout[i,:] = bf16(A @ B)     (B transposed bf16 [n][k])
// Block = 256 rows (wave w owns rows w*64..w*64+63, in 4 tiles of 16).
// B staged once per block into LDS in fragment-major order (conflict-free).
__global__ __launch_bounds__(256) void edge_mfma_v4(
    const bf16* __restrict__ base, const bf16* __restrict__ gin,
    const bf16* __restrict__ S, const int* __restrict__ from,
    const bf16* __restrict__ BT, bf16* __restrict__ gout, int fused)
{
    __shared__ bf16 Bsw[128 * 128];   // 32 KB
    int tid = threadIdx.x;

    // stage B, destination-consecutive (bank-conflict-free LDS writes)
    #pragma unroll
    for (int t = 0; t < 8; t++) {
        int c = tid + t * 256;            // dst chunk id 0..2047
        int cmr = c & 15;
        int cq  = (c >> 4) & 3;
        int ckt = (c >> 6) & 3;
        int cn  = c >> 8;
        int brow = cn * 16 + cmr;
        int bcol = ckt * 32 + cq * 8;
        *(bf16x8*)&Bsw[(size_t)c * 8] =
            *(const bf16x8*)(BT + (size_t)brow * 128 + bcol);
    }
    __syncthreads();

    int wave = tid >> 6, lane = tid & 63;
    int quad = lane >> 4, mr = lane & 15;

    #pragma unroll 1
    for (int it = 0; it < 4; ++it) {
        int i0 = blockIdx.x * 256 + wave * 64 + it * 16;
        if (i0 >= N_EDGES) break;         // N_EDGES % 16 == 0: tiles never split
        int i = i0 + mr;

        // ---- build this lane's 4 A-fragments in registers ----
        bf16x8 afr[4];
        if (!fused) {
            #pragma unroll
            for (int kt = 0; kt < 4; kt++) {
                bf16x8 bb = *(const bf16x8*)(base + (size_t)i * 128 + kt * 32 + quad * 8);
                #pragma unroll
                for (int j = 0; j < 8; j++)
                    afr[kt][j] = (bf16)fmaxf((float)bb[j], 0.f);
            }
        } else {
            const bf16* sr = S   + (size_t)from[i] * 128;
            const bf16* gr = gin + (size_t)(i ^ 1) * 128;
            #pragma unroll
            for (int kt = 0; kt < 4; kt++) {
                int c = kt * 32 + quad * 8;
                bf16x8 bb = *(const bf16x8*)(base + (size_t)i * 128 + c);
                bf16x8 gg = *(const bf16x8*)(gr + c);
                bf16x8 ss = *(const bf16x8*)(sr + c);
                #pragma unroll
                for (int j = 0; j < 8; j++) {
                    float v = (float)bb[j] + (float)ss[j] - (float)gg[j];
                    afr[kt][j] = (bf16)fmaxf(v, 0.f);
                }
            }
        }

        // ---- MFMA: 8 col-tiles x 4 k-chunks ----
        f32x4 acc[8];
        #pragma unroll
        for (int n = 0; n < 8; n++) acc[n] = (f32x4){0.f, 0.f, 0.f, 0.f};
        #pragma unroll
        for (int kt = 0; kt < 4; kt++) {
            #pragma unroll
            for (int n = 0; n < 8; n++) {
                bf16x8 b = *(const bf16x8*)&Bsw[(size_t)(((n * 4 + kt) * 64) + lane) * 8];
                acc[n] = __builtin_amdgcn_mfma_f32_16x16x32_bf16(afr[kt], b, acc[n], 0, 0, 0);
            }
        }

        // ---- epilogue: C/D layout col=mr, row=quad*4+reg; pack bf16x2 via
        // lane-pair shfl -> 4B stores, 64B segments ----
        #pragma unroll
        for (int np = 0; np < 4; np++) {
            int n0 = np * 2;
            #pragma unroll
            for (int reg = 0; reg < 4; reg++) {
                float v0 = acc[n0][reg], v1 = acc[n0 + 1][reg];
                float o0 = __shfl_xor(v0, 1);
                float o1 = __shfl_xor(v1, 1);
                bf16x2 pk;
                int colb;
                if ((mr & 1) == 0) {
                    pk[0] = (bf16)v0; pk[1] = (bf16)o0;
                    colb = n0 * 16 + mr;
                } else {
                    pk[0] = (bf16)o1; pk[1] = (bf16)v1;
                    colb = (n0 + 1) * 16 + (mr ^ 1);
                }
                int row = i0 + quad * 4 + reg;
                *(bf16x2*)(gout + (size_t)row * 128 + colb) = pk;
            }
        }
    }
}

// ---------------------------------------------------------------------------
// Segment sum with gather: S[n,:] = bf16( sum_{p=off[n]}^{off[n+1]} g[se[p],:] )
// High-occupancy latency-tolerant kernel (no LDS, 25k blocks, g rows L3-hot).
__global__ __launch_bounds__(256) void segsum_gather(
    const bf16* __restrict__ g, const int* __restrict__ se,
    const int* __restrict__ off, bf16* __restrict__ S)
{
    int n = blockIdx.x * 4 + (threadIdx.x >> 6);
    if (n >= N_NODES) return;
    int lane = threadIdx.x & 63;
    int o0 = off[n], o1 = off[n + 1];
    float a0 = 0.f, a1 = 0.f;
    for (int p = o0; p < o1; ++p) {
        int e = se[p];
        bf16x2 v = *(const bf16x2*)(g + (size_t)e * 128 + lane * 2);
        a0 += (float)v[0];
        a1 += (float)v[1];
    }
    bf16x2 o; o[0] = (bf16)a0; o[1] = (bf16)a1;
    *(bf16x2*)(S + (size_t)n * 128 + lane * 2) = o;
}

// ---------------------------------------------------------------------------
// Readout: in-edges of n are {se[p]^1 : p in bucket n} (to[i] = from[i^1]).
// out[n,:] = relu(U1x[n,:] + sum_bucket(gB[se[p]^1,:]) + deg[n]*U2b[:])
__global__ __launch_bounds__(256) void final_gather_out(
    const bf16* __restrict__ gB, const int* __restrict__ se,
    const int* __restrict__ off, const float* __restrict__ U1x,
    const float* __restrict__ U2b, float* __restrict__ out)
{
    int n = blockIdx.x * 4 + (threadIdx.x >> 6);
    if (n >= N_NODES) return;
    int lane = threadIdx.x & 63;
    int o0 = off[n], o1 = off[n + 1];
    float a0 = 0.f, a1 = 0.f;
    for (int p = o0; p < o1; ++p) {
        int e = se[p] ^ 1;
        bf16x2 v = *(const bf16x2*)(gB + (size_t)e * 128 + lane * 2);
        a0 += (float)v[0];
        a1 += (float)v[1];
    }
    float d = (float)(o1 - o0);
    float2 u = *(const float2*)(U1x + (size_t)n * 128 + lane * 2);
    float2 b = *(const float2*)(U2b + lane * 2);
    float r0 = fmaxf(u.x + a0 + d * b.x, 0.f);
    float r1 = fmaxf(u.y + a1 + d * b.y, 0.f);
    *(float2*)(out + (size_t)n * 128 + lane * 2) = make_float2(r0, r1);
}

// ---------------------------------------------------------------------------
extern "C" void kernel_launch(void* const* d_in, const int* in_sizes, int n_in,
                              void* d_out, int out_size, void* d_ws, size_t ws_size,
                              hipStream_t stream) {
    const float* nf  = (const float*)d_in[0];
    const float* ef  = (const float*)d_in[1];
    // d_in[2] edge_hiddens: zeros -> h1 = relu(base); first GEMM uses fused=0
    const int* edges = (const int*)d_in[3];
    const int* from  = edges;
    const float* W1w = (const float*)d_in[4];
    const float* W1b = (const float*)d_in[5];
    const float* W2w = (const float*)d_in[6];
    const float* W2b = (const float*)d_in[7];
    const float* W3w = (const float*)d_in[8];
    const float* W3b = (const float*)d_in[9];
    const float* U1w = (const float*)d_in[10];
    const float* U1b = (const float*)d_in[11];
    const float* U2w = (const float*)d_in[12];
    const float* U2b = (const float*)d_in[13];
    float* out = (float*)d_out;

    const size_t NODE_MAT = (size_t)N_NODES * 128;
    const size_t EDGE_MAT = (size_t)N_EDGES * 128;
    char* w = (char*)d_ws;
    float* nodeW1 = (float*)w; w += NODE_MAT * 4;        // reused as U1x
    bf16*  S      = (bf16*)w;  w += NODE_MAT * 2;
    bf16*  base   = (bf16*)w;  w += EDGE_MAT * 2;
    bf16*  g0     = (bf16*)w;  w += EDGE_MAT * 2;
    bf16*  g1     = (bf16*)w;  w += EDGE_MAT * 2;
    bf16*  W3T    = (bf16*)w;  w += 128 * 128 * 2;
    bf16*  U2T    = (bf16*)w;  w += 128 * 128 * 2;
    int*   deg    = (int*)w;   w += (size_t)N_NODES * 4;
    int*   off    = (int*)w;   w += (size_t)(N_NODES + 1) * 4;
    int*   cursor = (int*)w;   w += (size_t)N_NODES * 4;
    int*   bsum   = (int*)w;   w += (size_t)SCAN_BLOCKS * 4;
    int*   bpref  = (int*)w;   w += (size_t)SCAN_BLOCKS * 4;
    int*   se     = (int*)w;   w += (size_t)N_EDGES * 4;

    // ---- CSR build (only se + off needed downstream) ----
    hipMemsetAsync(deg, 0, (size_t)N_NODES * 4, stream);
    deg_hist<<<(N_EDGES + 255) / 256, 256, 0, stream>>>(from, deg, N_EDGES);
    block_sums<<<SCAN_BLOCKS, 256, 0, stream>>>(deg, bsum);
    scan_partials<<<1, 256, 0, stream>>>(bsum, bpref, off);
    block_scan<<<SCAN_BLOCKS, 256, 0, stream>>>(deg, bpref, off, cursor);
    scatter_csr<<<(N_EDGES + 255) / 256, 256, 0, stream>>>(from, cursor, se, N_EDGES);

    // ---- loop-invariant precompute ----
    prep_weights<<<(128 * 128 + 255) / 256, 256, 0, stream>>>(W3w, U2w, W3T, U2T);
    node_gemm<<<(N_NODES + 63) / 64, 256, 0, stream>>>(nf, W1w, W1b, nodeW1, N_NODES);
    base_orig<<<(N_EDGES + 511) / 512, 256, 0, stream>>>(
        nodeW1, from, ef, W2w, W2b, W3b, base);

    // ---- message passing (original edge order, ping-pong g) ----
    const int EGRID = (N_EDGES + 255) / 256;   // 2344
    const int SGRID = (N_NODES + 3) / 4;
    bf16* G[2] = {g0, g1};

    edge_mfma_v4<<<EGRID, 256, 0, stream>>>(base, G[0], S, from, W3T, G[0], 0);
    segsum_gather<<<SGRID, 256, 0, stream>>>(G[0], se, off, S);
    int cur = 0;
    for (int it = 1; it < 5; ++it) {
        edge_mfma_v4<<<EGRID, 256, 0, stream>>>(base, G[cur], S, from, W3T, G[cur ^ 1], 1);
        cur ^= 1;
        segsum_gather<<<SGRID, 256, 0, stream>>>(G[cur], se, off, S);
    }
    // ---- readout: h6 built in-flight with B = U2T ----
    edge_mfma_v4<<<EGRID, 256, 0, stream>>>(base, G[cur], S, from, U2T, G[cur ^ 1], 1);
    cur ^= 1;

    node_gemm<<<(N_NODES + 63) / 64, 256, 0, stream>>>(nf, U1w, U1b, nodeW1, N_NODES);
    final_gather_out<<<SGRID, 256, 0, stream>>>(G[cur], se, off, nodeW1, U2b, out);
}

// Round 3
// 1815.195 us; speedup vs baseline: 1.0664x; 1.0201x over previous
//
#include <hip/hip_runtime.h>
#include <hip/hip_bf16.h>

#define N_NODES 100000
#define N_EDGES 600000
#define SCAN_BLOCKS ((N_NODES + 255) / 256)   // 391

typedef __bf16 bf16;
typedef __bf16 bf16x2 __attribute__((ext_vector_type(2)));
typedef __bf16 bf16x4 __attribute__((ext_vector_type(4)));
typedef __bf16 bf16x8 __attribute__((ext_vector_type(8)));
typedef float f32x4 __attribute__((ext_vector_type(4)));

// ---------------------------------------------------------------------------
// deg[n] = #edges with from==n (== to-degree by reverse-pair symmetry)
__global__ void deg_hist(const int* __restrict__ from, int* __restrict__ deg, int E) {
    int e = blockIdx.x * blockDim.x + threadIdx.x;
    if (e < E) atomicAdd(&deg[from[e]], 1);
}

// ---- CSR build ----
__global__ __launch_bounds__(256) void block_sums(
    const int* __restrict__ deg, int* __restrict__ bsum)
{
    __shared__ int s[256];
    int i = blockIdx.x * 256 + threadIdx.x;
    s[threadIdx.x] = (i < N_NODES) ? deg[i] : 0;
    __syncthreads();
    for (int st = 128; st > 0; st >>= 1) {
        if (threadIdx.x < st) s[threadIdx.x] += s[threadIdx.x + st];
        __syncthreads();
    }
    if (threadIdx.x == 0) bsum[blockIdx.x] = s[0];
}

__global__ __launch_bounds__(256) void scan_partials(
    const int* __restrict__ bsum, int* __restrict__ bpref, int* __restrict__ off)
{
    __shared__ int s[SCAN_BLOCKS];
    for (int i = threadIdx.x; i < SCAN_BLOCKS; i += 256) s[i] = bsum[i];
    __syncthreads();
    if (threadIdx.x == 0) {
        int run = 0;
        for (int i = 0; i < SCAN_BLOCKS; i++) { int t = s[i]; s[i] = run; run += t; }
        off[N_NODES] = run;   // == N_EDGES
    }
    __syncthreads();
    for (int i = threadIdx.x; i < SCAN_BLOCKS; i += 256) bpref[i] = s[i];
}

__global__ __launch_bounds__(256) void block_scan(
    const int* __restrict__ deg, const int* __restrict__ bpref,
    int* __restrict__ off, int* __restrict__ cursor)
{
    __shared__ int s[256];
    int i = blockIdx.x * 256 + threadIdx.x;
    int v = (i < N_NODES) ? deg[i] : 0;
    s[threadIdx.x] = v;
    __syncthreads();
    for (int st = 1; st < 256; st <<= 1) {
        int x = (threadIdx.x >= st) ? s[threadIdx.x - st] : 0;
        __syncthreads();
        s[threadIdx.x] += x;
        __syncthreads();
    }
    if (i < N_NODES) {
        int o = bpref[blockIdx.x] + s[threadIdx.x] - v;   // exclusive
        off[i] = o;
        cursor[i] = o;
    }
}

// se[p] = e (sorted by from), rank[e] = p
__global__ void scatter_csr(const int* __restrict__ from, int* __restrict__ cursor,
                            int* __restrict__ se, int* __restrict__ rank, int E) {
    int e = blockIdx.x * blockDim.x + threadIdx.x;
    if (e < E) {
        int p = atomicAdd(&cursor[from[e]], 1);
        se[p] = e;
        rank[e] = p;
    }
}

// fromP[i] = from[se[i]]; backP[i] = rank[se[i]^1]   (backP is an involution)
__global__ void make_maps(const int* __restrict__ se, const int* __restrict__ from,
                          const int* __restrict__ rank,
                          int* __restrict__ fromP, int* __restrict__ backP, int E) {
    int i = blockIdx.x * blockDim.x + threadIdx.x;
    if (i < E) {
        int e = se[i];
        fromP[i] = from[e];
        backP[i] = rank[e ^ 1];
    }
}

// ---------------------------------------------------------------------------
// C[M,128] = A[M,64] @ B[64,128] + bias   (node-side GEMM, K=64, fp32 vector)
__global__ __launch_bounds__(256) void node_gemm(
    const float* __restrict__ A, const float* __restrict__ B,
    const float* __restrict__ bias, float* __restrict__ C, int M)
{
    __shared__ float As[16][65];
    __shared__ float Bs[16][128];
    int row0 = blockIdx.x * 64;
    int tid = threadIdx.x;
    int tx = tid & 15, ty = tid >> 4;
    float acc[4][8];
    #pragma unroll
    for (int i = 0; i < 4; i++)
        #pragma unroll
        for (int j = 0; j < 8; j++) acc[i][j] = 0.f;

    for (int kk = 0; kk < 64; kk += 16) {
        int m  = tid >> 2;
        int k4 = (tid & 3) * 4;
        float4 v = make_float4(0.f, 0.f, 0.f, 0.f);
        if (row0 + m < M)
            v = *(const float4*)(A + (size_t)(row0 + m) * 64 + kk + k4);
        As[k4 + 0][m] = v.x; As[k4 + 1][m] = v.y;
        As[k4 + 2][m] = v.z; As[k4 + 3][m] = v.w;
        #pragma unroll
        for (int t = 0; t < 2; t++) {
            int id = tid + t * 256;
            int k = id >> 5, n4 = (id & 31) * 4;
            *(float4*)(&Bs[k][n4]) = *(const float4*)(B + (size_t)(kk + k) * 128 + n4);
        }
        __syncthreads();
        #pragma unroll
        for (int k = 0; k < 16; k++) {
            float a[4], b[8];
            #pragma unroll
            for (int i = 0; i < 4; i++) a[i] = As[k][ty * 4 + i];
            #pragma unroll
            for (int j = 0; j < 8; j++) b[j] = Bs[k][tx + j * 16];
            #pragma unroll
            for (int i = 0; i < 4; i++)
                #pragma unroll
                for (int j = 0; j < 8; j++) acc[i][j] += a[i] * b[j];
        }
        __syncthreads();
    }
    #pragma unroll
    for (int i = 0; i < 4; i++) {
        int r = row0 + ty * 4 + i;
        if (r < M) {
            #pragma unroll
            for (int j = 0; j < 8; j++) {
                int c = tx + j * 16;
                C[(size_t)r * 128 + c] = acc[i][j] + bias[c];
            }
        }
    }
}

// ---------------------------------------------------------------------------
// baseP[i,:] = bf16( nodeW1[fromP[i],:] + ef[se[i],:16]@W2 + (W2_b+W3_b) )
// Sorted edge space: nodeW1 gather has sort locality.
__global__ __launch_bounds__(256) void base_sorted(
    const float* __restrict__ nodeW1, const int* __restrict__ fromP,
    const int* __restrict__ se, const float* __restrict__ ef,
    const float* __restrict__ W2, const float* __restrict__ W2b,
    const float* __restrict__ W3b, bf16* __restrict__ baseP)
{
    int tid = threadIdx.x;
    int c0 = (tid & 31) * 4;
    int sub = tid >> 5;                  // 8 edge slots
    float4 w[16];
    #pragma unroll
    for (int k = 0; k < 16; k++) w[k] = *(const float4*)(W2 + k * 128 + c0);
    float4 bias;
    {
        float4 a = *(const float4*)(W2b + c0);
        float4 b = *(const float4*)(W3b + c0);
        bias = make_float4(a.x + b.x, a.y + b.y, a.z + b.z, a.w + b.w);
    }
    #pragma unroll 1
    for (int it = 0; it < 64; ++it) {
        int i = blockIdx.x * 512 + it * 8 + sub;
        if (i >= N_EDGES) break;
        const float* efr = ef + (size_t)se[i] * 16;
        float4 nv = *(const float4*)(nodeW1 + (size_t)fromP[i] * 128 + c0);
        float4 acc = make_float4(bias.x + nv.x, bias.y + nv.y,
                                 bias.z + nv.z, bias.w + nv.w);
        #pragma unroll
        for (int k = 0; k < 16; k++) {
            float s = efr[k];
            acc.x += s * w[k].x; acc.y += s * w[k].y;
            acc.z += s * w[k].z; acc.w += s * w[k].w;
        }
        bf16x4 o;
        o[0] = (bf16)acc.x; o[1] = (bf16)acc.y; o[2] = (bf16)acc.z; o[3] = (bf16)acc.w;
        *(bf16x4*)(baseP + (size_t)i * 128 + c0) = o;
    }
}

// ---------------------------------------------------------------------------
// W3T[n][k] = bf16(W3[k][n]);  U2T[n][k] = bf16(U2[k][n])   (one-time)
__global__ __launch_bounds__(256) void prep_weights(
    const float* __restrict__ W3, const float* __restrict__ U2,
    bf16* __restrict__ W3T, bf16* __restrict__ U2T)
{
    int i = blockIdx.x * 256 + threadIdx.x;
    if (i < 128 * 128) {
        int k = i >> 7, n = i & 127;
        W3T[n * 128 + k] = (bf16)W3[k * 128 + n];
        U2T[n * 128 + k] = (bf16)U2[k * 128 + n];
    }
}

// ---------------------------------------------------------------------------
// Edge-step GEMM v5 (bf16 MFMA), sorted space, ZERO random reads:
//   A[i,:] = fused ? relu(baseP[i] + S[fromP[i]] - gBP[i]) : relu(baseP[i])
//   gout[orow(i),:] = bf16(A @ B)   (orow = backP[i] when scatter, else i)
// gBP[i] == g_prev[backP[i]] was materialized by the previous segsum's
// involution scatter-write, so the backlink read is a coalesced STREAM.
// S[fromP[i]] has sort locality (consecutive rows share the from-node).
// B staged once per block into LDS in fragment-major order (conflict-free).
__global__ __launch_bounds__(256) void edge_mfma_v5(
    const bf16* __restrict__ baseP, const bf16* __restrict__ gBP,
    const bf16* __restrict__ S, const int* __restrict__ fromP,
    const int* __restrict__ backP, const bf16* __restrict__ BT,
    bf16* __restrict__ gout, int fused, int scatter)
{
    __shared__ bf16 Bsw[128 * 128];   // 32 KB
    int tid = threadIdx.x;

    // stage B, destination-consecutive (bank-conflict-free LDS writes)
    #pragma unroll
    for (int t = 0; t < 8; t++) {
        int c = tid + t * 256;            // dst chunk id 0..2047
        int cmr = c & 15;
        int cq  = (c >> 4) & 3;
        int ckt = (c >> 6) & 3;
        int cn  = c >> 8;
        int brow = cn * 16 + cmr;
        int bcol = ckt * 32 + cq * 8;
        *(bf16x8*)&Bsw[(size_t)c * 8] =
            *(const bf16x8*)(BT + (size_t)brow * 128 + bcol);
    }
    __syncthreads();

    int wave = tid >> 6, lane = tid & 63;
    int quad = lane >> 4, mr = lane & 15;

    #pragma unroll 1
    for (int it = 0; it < 4; ++it) {
        int i0 = blockIdx.x * 256 + wave * 64 + it * 16;
        if (i0 >= N_EDGES) break;         // N_EDGES % 16 == 0: tiles never split
        int i = i0 + mr;

        // ---- build this lane's 4 A-fragments in registers ----
        bf16x8 afr[4];
        if (!fused) {
            #pragma unroll
            for (int kt = 0; kt < 4; kt++) {
                bf16x8 bb = *(const bf16x8*)(baseP + (size_t)i * 128 + kt * 32 + quad * 8);
                #pragma unroll
                for (int j = 0; j < 8; j++)
                    afr[kt][j] = (bf16)fmaxf((float)bb[j], 0.f);
            }
        } else {
            const bf16* sr = S   + (size_t)fromP[i] * 128;
            const bf16* gr = gBP + (size_t)i * 128;        // STREAM read
            #pragma unroll
            for (int kt = 0; kt < 4; kt++) {
                int c = kt * 32 + quad * 8;
                bf16x8 bb = *(const bf16x8*)(baseP + (size_t)i * 128 + c);
                bf16x8 gg = *(const bf16x8*)(gr + c);
                bf16x8 ss = *(const bf16x8*)(sr + c);
                #pragma unroll
                for (int j = 0; j < 8; j++) {
                    float v = (float)bb[j] + (float)ss[j] - (float)gg[j];
                    afr[kt][j] = (bf16)fmaxf(v, 0.f);
                }
            }
        }

        // ---- MFMA: 8 col-tiles x 4 k-chunks ----
        f32x4 acc[8];
        #pragma unroll
        for (int n = 0; n < 8; n++) acc[n] = (f32x4){0.f, 0.f, 0.f, 0.f};
        #pragma unroll
        for (int kt = 0; kt < 4; kt++) {
            #pragma unroll
            for (int n = 0; n < 8; n++) {
                bf16x8 b = *(const bf16x8*)&Bsw[(size_t)(((n * 4 + kt) * 64) + lane) * 8];
                acc[n] = __builtin_amdgcn_mfma_f32_16x16x32_bf16(afr[kt], b, acc[n], 0, 0, 0);
            }
        }

        // ---- epilogue: C/D layout col=mr, row=quad*4+reg; pack bf16x2 via
        // lane-pair shfl -> 4B stores. Optional involution-scatter to backP
        // (used only by the U2 readout step; latency-tolerant writes). ----
        int rbase4 = i0 + quad * 4;
        int orow[4];
        #pragma unroll
        for (int reg = 0; reg < 4; reg++)
            orow[reg] = scatter ? backP[rbase4 + reg] : (rbase4 + reg);

        #pragma unroll
        for (int np = 0; np < 4; np++) {
            int n0 = np * 2;
            #pragma unroll
            for (int reg = 0; reg < 4; reg++) {
                float v0 = acc[n0][reg], v1 = acc[n0 + 1][reg];
                float o0 = __shfl_xor(v0, 1);
                float o1 = __shfl_xor(v1, 1);
                bf16x2 pk;
                int colb;
                if ((mr & 1) == 0) {
                    pk[0] = (bf16)v0; pk[1] = (bf16)o0;
                    colb = n0 * 16 + mr;
                } else {
                    pk[0] = (bf16)o1; pk[1] = (bf16)v1;
                    colb = (n0 + 1) * 16 + (mr ^ 1);
                }
                *(bf16x2*)(gout + (size_t)orow[reg] * 128 + colb) = pk;
            }
        }
    }
}

// ---------------------------------------------------------------------------
// Streaming segment sum + involution scatter:
//   S[n,:]            = bf16( sum_{p in bucket n} g[p,:] )      (stream read)
//   gBPout[backP[p]]  = g[p,:]                                  (row scatter)
// The scatter is fire-and-forget: 256B contiguous per row = 4 full lines.
// Next edge kernel then reads gBPout as a pure stream.
__global__ __launch_bounds__(256) void segsum_scatter(
    const bf16* __restrict__ g, const int* __restrict__ backP,
    const int* __restrict__ off, bf16* __restrict__ S,
    bf16* __restrict__ gBPout)
{
    int n = blockIdx.x * 4 + (threadIdx.x >> 6);
    if (n >= N_NODES) return;
    int lane = threadIdx.x & 63;
    int o0 = off[n], o1 = off[n + 1];
    float a0 = 0.f, a1 = 0.f;
    for (int p = o0; p < o1; ++p) {
        bf16x2 v = *(const bf16x2*)(g + (size_t)p * 128 + lane * 2);
        a0 += (float)v[0];
        a1 += (float)v[1];
        int q = backP[p];   // wave-uniform
        *(bf16x2*)(gBPout + (size_t)q * 128 + lane * 2) = v;
    }
    bf16x2 o; o[0] = (bf16)a0; o[1] = (bf16)a1;
    *(bf16x2*)(S + (size_t)n * 128 + lane * 2) = o;
}

// ---------------------------------------------------------------------------
// Readout: X[q] = U2h[backP[q]] (written by the scatter epilogue), so the
// in-edge sum of node n is the CONTIGUOUS bucket [off[n], off[n+1]) of X.
// out[n,:] = relu(U1x[n,:] + sum_bucket(X) + deg[n]*U2b[:])
__global__ __launch_bounds__(256) void final_out_stream(
    const bf16* __restrict__ X, const int* __restrict__ off,
    const float* __restrict__ U1x, const float* __restrict__ U2b,
    float* __restrict__ out)
{
    int n = blockIdx.x * 4 + (threadIdx.x >> 6);
    if (n >= N_NODES) return;
    int lane = threadIdx.x & 63;
    int o0 = off[n], o1 = off[n + 1];
    float a0 = 0.f, a1 = 0.f;
    for (int p = o0; p < o1; ++p) {
        bf16x2 v = *(const bf16x2*)(X + (size_t)p * 128 + lane * 2);
        a0 += (float)v[0];
        a1 += (float)v[1];
    }
    float d = (float)(o1 - o0);
    float2 u = *(const float2*)(U1x + (size_t)n * 128 + lane * 2);
    float2 b = *(const float2*)(U2b + lane * 2);
    float r0 = fmaxf(u.x + a0 + d * b.x, 0.f);
    float r1 = fmaxf(u.y + a1 + d * b.y, 0.f);
    *(float2*)(out + (size_t)n * 128 + lane * 2) = make_float2(r0, r1);
}

// ---------------------------------------------------------------------------
extern "C" void kernel_launch(void* const* d_in, const int* in_sizes, int n_in,
                              void* d_out, int out_size, void* d_ws, size_t ws_size,
                              hipStream_t stream) {
    const float* nf  = (const float*)d_in[0];
    const float* ef  = (const float*)d_in[1];
    // d_in[2] edge_hiddens: zeros -> h1 = relu(base); first GEMM uses fused=0
    const int* edges = (const int*)d_in[3];
    const int* from  = edges;
    const float* W1w = (const float*)d_in[4];
    const float* W1b = (const float*)d_in[5];
    const float* W2w = (const float*)d_in[6];
    const float* W2b = (const float*)d_in[7];
    const float* W3w = (const float*)d_in[8];
    const float* W3b = (const float*)d_in[9];
    const float* U1w = (const float*)d_in[10];
    const float* U1b = (const float*)d_in[11];
    const float* U2w = (const float*)d_in[12];
    const float* U2b = (const float*)d_in[13];
    float* out = (float*)d_out;

    const size_t NODE_MAT = (size_t)N_NODES * 128;
    const size_t EDGE_MAT = (size_t)N_EDGES * 128;
    char* w = (char*)d_ws;
    float* nodeW1 = (float*)w; w += NODE_MAT * 4;        // reused as U1x
    bf16*  S      = (bf16*)w;  w += NODE_MAT * 2;
    bf16*  baseP  = (bf16*)w;  w += EDGE_MAT * 2;
    bf16*  G      = (bf16*)w;  w += EDGE_MAT * 2;        // edge-order g / X
    bf16*  GBP    = (bf16*)w;  w += EDGE_MAT * 2;        // backlink-order g
    bf16*  W3T    = (bf16*)w;  w += 128 * 128 * 2;
    bf16*  U2T    = (bf16*)w;  w += 128 * 128 * 2;
    int*   deg    = (int*)w;   w += (size_t)N_NODES * 4;
    int*   off    = (int*)w;   w += (size_t)(N_NODES + 1) * 4;
    int*   cursor = (int*)w;   w += (size_t)N_NODES * 4;
    int*   bsum   = (int*)w;   w += (size_t)SCAN_BLOCKS * 4;
    int*   bpref  = (int*)w;   w += (size_t)SCAN_BLOCKS * 4;
    int*   se     = (int*)w;   w += (size_t)N_EDGES * 4;
    int*   rank   = (int*)w;   w += (size_t)N_EDGES * 4;
    int*   fromP  = (int*)w;   w += (size_t)N_EDGES * 4;
    int*   backP  = (int*)w;   w += (size_t)N_EDGES * 4;

    // ---- CSR build + sorted-space maps ----
    hipMemsetAsync(deg, 0, (size_t)N_NODES * 4, stream);
    deg_hist<<<(N_EDGES + 255) / 256, 256, 0, stream>>>(from, deg, N_EDGES);
    block_sums<<<SCAN_BLOCKS, 256, 0, stream>>>(deg, bsum);
    scan_partials<<<1, 256, 0, stream>>>(bsum, bpref, off);
    block_scan<<<SCAN_BLOCKS, 256, 0, stream>>>(deg, bpref, off, cursor);
    scatter_csr<<<(N_EDGES + 255) / 256, 256, 0, stream>>>(from, cursor, se, rank, N_EDGES);
    make_maps<<<(N_EDGES + 255) / 256, 256, 0, stream>>>(se, from, rank, fromP, backP, N_EDGES);

    // ---- loop-invariant precompute ----
    prep_weights<<<(128 * 128 + 255) / 256, 256, 0, stream>>>(W3w, U2w, W3T, U2T);
    node_gemm<<<(N_NODES + 63) / 64, 256, 0, stream>>>(nf, W1w, W1b, nodeW1, N_NODES);
    base_sorted<<<(N_EDGES + 511) / 512, 256, 0, stream>>>(
        nodeW1, fromP, se, ef, W2w, W2b, W3b, baseP);

    // ---- message passing (sorted space, all-stream) ----
    const int EGRID = (N_EDGES + 255) / 256;   // 2344
    const int SGRID = (N_NODES + 3) / 4;

    // g1 = relu(base) @ W3
    edge_mfma_v5<<<EGRID, 256, 0, stream>>>(
        baseP, GBP, S, fromP, backP, W3T, G, 0, 0);
    segsum_scatter<<<SGRID, 256, 0, stream>>>(G, backP, off, S, GBP);
    for (int it = 1; it < 5; ++it) {
        edge_mfma_v5<<<EGRID, 256, 0, stream>>>(
            baseP, GBP, S, fromP, backP, W3T, G, 1, 0);
        segsum_scatter<<<SGRID, 256, 0, stream>>>(G, backP, off, S, GBP);
    }
    // readout: h6 built in-flight, B = U2T, epilogue scatters through backP
    // so the to-side sum becomes a contiguous bucket stream of G.
    edge_mfma_v5<<<EGRID, 256, 0, stream>>>(
        baseP, GBP, S, fromP, backP, U2T, G, 1, 1);

    node_gemm<<<(N_NODES + 63) / 64, 256, 0, stream>>>(nf, U1w, U1b, nodeW1, N_NODES);
    final_out_stream<<<SGRID, 256, 0, stream>>>(G, off, nodeW1, U2b, out);
}